// Round 1
// baseline (142.414 us; speedup 1.0000x reference)
//
#include <hip/hip_runtime.h>

typedef _Float16 half_t;
typedef half_t f16x8 __attribute__((ext_vector_type(8)));
typedef float f32x4 __attribute__((ext_vector_type(4)));
typedef unsigned int u32x2 __attribute__((ext_vector_type(2)));

#define LOG2E 1.44269504088896340736f

// Problem dims (fixed)
#define NROWS 65536
#define DIN   64
#define NCTRS 1024
#define DOUT  256

// Workspace layout (bytes). ONE FRAGMENT = 64 lanes x 16 B = 1024 B.
#define CSWZ_OFF 0
#define CSWZ_BYTES (128 * 1024)
#define VSWZ_OFF (CSWZ_OFF + CSWZ_BYTES)            // 131072
#define VSWZ_BYTES (512 * 1024)
#define CSQ_OFF  (VSWZ_OFF + VSWZ_BYTES)            // 655360; end 659456

#define VT_STRIDE 260   // 256 + 4 pad
#define CT_STRIDE 68

// defer-max threshold in log2 units: p <= 2^8 = 256, safely inside f16 range
#define RESCALE_THR 8.0f

// async global->LDS, 16 B per lane, linear pattern (dest = uniform base + lane*16)
#define GLOAD_LDS16(g, l)                                                      \
  __builtin_amdgcn_global_load_lds(                                            \
      (const __attribute__((address_space(1))) void*)(const void*)(g),         \
      (__attribute__((address_space(3))) void*)(void*)(l), 16, 0, 0)

// ---------------------------------------------------------------------------
// Precompute: one block per 32-center chunk. float4 global loads into LDS
// tiles, then frag-layout stores. Fragment layout (A/B symmetric):
//   lane holds [idx = lane&15][k = 8*(lane>>4) + j], j=0..7 (16 B contiguous)
// ---------------------------------------------------------------------------
__global__ __launch_bounds__(256) void precompute_kernel(
    const float* __restrict__ ctrs, const float* __restrict__ values,
    const float* __restrict__ s, char* __restrict__ ws) {
  half_t* Cswz = (half_t*)(ws + CSWZ_OFF);
  half_t* Vswz = (half_t*)(ws + VSWZ_OFF);
  float* csq2 = (float*)(ws + CSQ_OFF);

  __shared__ half_t Vt[32 * VT_STRIDE];  // 32 x 256 (padded)
  __shared__ half_t Ct[32 * CT_STRIDE];  // 32 x 64  (padded)

  const int c = blockIdx.x, tid = threadIdx.x;

  // V tile: 32x256 floats = 2048 float4, 8 per thread
#pragma unroll
  for (int i = 0; i < 8; ++i) {
    int idx = i * 256 + tid;
    int r = idx >> 6, c4 = (idx & 63) * 4;
    float4 v = ((const float4*)values)[(size_t)(c * 32 + r) * 64 + (idx & 63)];
    Vt[r * VT_STRIDE + c4 + 0] = (half_t)v.x;
    Vt[r * VT_STRIDE + c4 + 1] = (half_t)v.y;
    Vt[r * VT_STRIDE + c4 + 2] = (half_t)v.z;
    Vt[r * VT_STRIDE + c4 + 3] = (half_t)v.w;
  }
  // C tile: 32x64 floats = 512 float4, 2 per thread
#pragma unroll
  for (int i = 0; i < 2; ++i) {
    int idx = i * 256 + tid;
    int r = idx >> 4, c4 = (idx & 15) * 4;
    float4 v = ((const float4*)ctrs)[(size_t)(c * 32 + r) * 16 + (idx & 15)];
    Ct[r * CT_STRIDE + c4 + 0] = (half_t)v.x;
    Ct[r * CT_STRIDE + c4 + 1] = (half_t)v.y;
    Ct[r * CT_STRIDE + c4 + 2] = (half_t)v.z;
    Ct[r * CT_STRIDE + c4 + 3] = (half_t)v.w;
  }
  // csq2: k = tid>>3, 8 lanes each sum 8 d's, shuffle-reduce
  {
    int k = tid >> 3, dg = (tid & 7) * 8;
    const float* cp = ctrs + (size_t)(c * 32 + k) * DIN + dg;
    float acc = 0.0f;
#pragma unroll
    for (int j = 0; j < 8; ++j) acc = fmaf(cp[j] * cp[j], s[dg + j], acc);
    acc += __shfl_xor(acc, 1);
    acc += __shfl_xor(acc, 2);
    acc += __shfl_xor(acc, 4);
    if ((tid & 7) == 0) csq2[c * 32 + k] = acc * LOG2E;
  }
  __syncthreads();

  const int w = tid >> 6, l = tid & 63, l4 = l >> 4, lm = l & 15;

  {  // Cswz: frag f = w; ct = f>>1, kt = f&1
    int ct = w >> 1, kt = w & 1;
    f16x8 v;
#pragma unroll
    for (int j = 0; j < 8; ++j)
      v[j] = Ct[(ct * 16 + lm) * CT_STRIDE + kt * 32 + l4 * 8 + j];
    *(f16x8*)(Cswz + ((c * 4 + w) * 64 + l) * 8) = v;
  }
#pragma unroll
  for (int q = 0; q < 4; ++q) {  // Vswz: 16 frags, 4 per wave
    int sl = w * 4 + q;
    f16x8 v;
#pragma unroll
    for (int j = 0; j < 8; ++j)
      v[j] = Vt[(l4 * 8 + j) * VT_STRIDE + sl * 16 + lm];
    *(f16x8*)(Vswz + ((c * 16 + sl) * 64 + l) * 8) = v;
  }
}

// ---------------------------------------------------------------------------
// Fused kernel, SINGLE-PASS online softmax with defer-max, swapped operands:
//   QK^T: S^T = mfma(C_frag, X_frag)  -> lane holds scores for centers
//         c = ct*16 + l4*4 + j, row r = lm. Row max is 7 fmax + 2 shfl_xor.
//   P^T built IN REGISTERS: f16-pack pairs then permlane32_swap +
//   permlane16_swap route (ct,g',jj) -> PV B-frag words:
//     X,Y = permlane32_swap(A=q[ct0][h], B=q[ct1][h])
//         X={A@0,A@1,B@0,B@1}, Y={A@2,A@3,B@2,B@3}
//     W0,W2 = permlane16_swap(X,Y) = {A@0,A@2,B@0,B@2},{A@1,A@3,B@1,B@3}
//   PV: O^T = mfma(V_frag, P_frag)  -> Vswz layout unchanged (A/B symmetric),
//   output O^T[dout][r] gives contiguous dwordx4 epilogue stores.
//   V chunks (16 KB) double-buffered in LDS via global_load_lds: one DMA per
//   BLOCK per chunk instead of per wave (4x cut in L2 V-demand).
// Block = 128 rows x 1024 ctrs (4 waves x 32 rows). One barrier per chunk.
// scores = (2*cross - csq)*log2e  (x^2 term cancels in softmax).
// ---------------------------------------------------------------------------
__global__ __launch_bounds__(256, 2) void attn_kernel(
    const float* __restrict__ x, const float* __restrict__ s,
    const char* __restrict__ ws, float* __restrict__ out) {
  const f16x8* cbase = (const f16x8*)(ws + CSWZ_OFF);
  const char* Vraw = ws + VSWZ_OFF;
  const float* csq2 = (const float*)(ws + CSQ_OFF);

  __shared__ __attribute__((aligned(16))) char vbuf[2][16384];

  const int tid = threadIdx.x;
  const int w = tid >> 6, l = tid & 63, l4 = l >> 4, lm = l & 15;
  const int rowbase = blockIdx.x * 128 + w * 32;

  // stage V chunk 0 (in flight across the x-load prologue)
#pragma unroll
  for (int i = 0; i < 4; ++i) {
    GLOAD_LDS16(Vraw + i * 4096 + tid * 16, &vbuf[0][i * 4096 + w * 1024]);
  }

  // ---- x*s fragments in registers (used as the MFMA B-operand now)
  f16x8 A[2][2];
#pragma unroll
  for (int rt = 0; rt < 2; ++rt) {
#pragma unroll
    for (int kt = 0; kt < 2; ++kt) {
      int din = kt * 32 + l4 * 8;
      const float* src = x + (rowbase + rt * 16 + lm) * DIN + din;
      f16x8 a;
#pragma unroll
      for (int j = 0; j < 8; ++j) a[j] = (half_t)(src[j] * s[din + j]);
      A[rt][kt] = a;
    }
  }

  // all-ones row-0 A-frag for the L (row-sum) MFMA: A[0][k]=1 for all k
  f16x8 ones;
#pragma unroll
  for (int j = 0; j < 8; ++j) ones[j] = (lm == 0) ? (half_t)1.0f : (half_t)0.0f;

  f32x4 O[2][16];   // O^T: lane holds [dout=u*16+l4*4+j][r=lm]
  f32x4 Lacc[2];    // row sums via ones-MFMA (row 0 of D, consistent f16 P)
  float m[2] = {-1e30f, -1e30f};  // running (deferred) max for row r=lm
#pragma unroll
  for (int rt = 0; rt < 2; ++rt) {
    Lacc[rt] = (f32x4){0.f, 0.f, 0.f, 0.f};
#pragma unroll
    for (int u = 0; u < 16; ++u) O[rt][u] = (f32x4){0.f, 0.f, 0.f, 0.f};
  }

#pragma unroll 1
  for (int c = 0; c < 32; ++c) {
    const int cur = c & 1;
    // my chunk-c DMA (and all older vmem) retired -> workgroup-wide ready.
    // vmcnt(0) is spill-immune and ~free: the DMA flew across chunk c-1.
    asm volatile("s_waitcnt vmcnt(0)" ::: "memory");
    __builtin_amdgcn_s_barrier();
    __builtin_amdgcn_sched_barrier(0);

    // chunk-c register loads BEFORE the next DMA issue, so the compiler's
    // counted waits for these never drain the in-flight stage.
    f16x8 b0 = cbase[(c * 4 + 0) * 64 + l];
    f16x8 b1 = cbase[(c * 4 + 1) * 64 + l];
    f16x8 b2 = cbase[(c * 4 + 2) * 64 + l];
    f16x8 b3 = cbase[(c * 4 + 3) * 64 + l];
    f32x4 cs0 = *(const f32x4*)(csq2 + c * 32 + l4 * 4);
    f32x4 cs1 = *(const f32x4*)(csq2 + c * 32 + 16 + l4 * 4);
    __builtin_amdgcn_sched_barrier(0);

    if (c < 31) {  // async prefetch next V chunk into the other buffer
      const char* src = Vraw + (size_t)(c + 1) * 16384;
#pragma unroll
      for (int i = 0; i < 4; ++i) {
        GLOAD_LDS16(src + i * 4096 + tid * 16,
                    &vbuf[cur ^ 1][i * 4096 + w * 1024]);
      }
    }
    __builtin_amdgcn_sched_barrier(0);

    f16x8 pb[2];
#pragma unroll
    for (int rt = 0; rt < 2; ++rt) {
      // swapped QK^T: rows = centers (l4*4+j), cols = x-rows (lm)
      f32x4 t0 = {0.f, 0.f, 0.f, 0.f}, t1 = {0.f, 0.f, 0.f, 0.f};
      t0 = __builtin_amdgcn_mfma_f32_16x16x32_f16(b0, A[rt][0], t0, 0, 0, 0);
      t0 = __builtin_amdgcn_mfma_f32_16x16x32_f16(b1, A[rt][1], t0, 0, 0, 0);
      t1 = __builtin_amdgcn_mfma_f32_16x16x32_f16(b2, A[rt][0], t1, 0, 0, 0);
      t1 = __builtin_amdgcn_mfma_f32_16x16x32_f16(b3, A[rt][1], t1, 0, 0, 0);

      float v0[4], v1[4];
      float pm = -1e30f;
#pragma unroll
      for (int j = 0; j < 4; ++j) {
        v0[j] = fmaf(t0[j], 2.0f * LOG2E, -cs0[j]);
        v1[j] = fmaf(t1[j], 2.0f * LOG2E, -cs1[j]);
        pm = fmaxf(pm, fmaxf(v0[j], v1[j]));
      }
      // per-lane partial max -> exact row max (rows live in lm; reduce l4)
      pm = fmaxf(pm, __shfl_xor(pm, 16));
      pm = fmaxf(pm, __shfl_xor(pm, 32));

      // defer-max: rescale only when some row's max grew past THR
      if (__any(pm > m[rt] + RESCALE_THR)) {
        float mn = fmaxf(m[rt], pm);
        float f = __builtin_amdgcn_exp2f(m[rt] - mn);  // per-lane (row lm)
        m[rt] = mn;
        Lacc[rt] *= f;
#pragma unroll
        for (int u = 0; u < 16; ++u) O[rt][u] *= f;
      }

      // p = exp2(v - m) <= 2^THR; RTN f16 pack (matches verified kernel's
      // rounding); permlane-route into the PV B-frag
      unsigned wds[4];
#pragma unroll
      for (int h = 0; h < 2; ++h) {
        union { half_t h2[2]; unsigned u; } qa, qb;
        qa.h2[0] = (half_t)__builtin_amdgcn_exp2f(v0[2 * h] - m[rt]);
        qa.h2[1] = (half_t)__builtin_amdgcn_exp2f(v0[2 * h + 1] - m[rt]);
        qb.h2[0] = (half_t)__builtin_amdgcn_exp2f(v1[2 * h] - m[rt]);
        qb.h2[1] = (half_t)__builtin_amdgcn_exp2f(v1[2 * h + 1] - m[rt]);
        u32x2 sw1 = __builtin_amdgcn_permlane32_swap(qa.u, qb.u, false, false);
        u32x2 sw2 = __builtin_amdgcn_permlane16_swap(sw1.x, sw1.y, false, false);
        wds[h] = sw2.x;       // word h   : elements 2h,2h+1
        wds[h + 2] = sw2.y;   // word h+2 : elements 2h+4,2h+5
      }
      union { unsigned u[4]; f16x8 v; } pk;
      pk.u[0] = wds[0]; pk.u[1] = wds[1]; pk.u[2] = wds[2]; pk.u[3] = wds[3];
      pb[rt] = pk.v;
    }

    // ---- PV (swapped): O^T += V^T * P^T ; V frags from staged LDS
    const char* vb = &vbuf[cur][l * 16];
#pragma unroll
    for (int u = 0; u < 16; ++u) {
      f16x8 vf = *(const f16x8*)(vb + u * 1024);
      O[0][u] = __builtin_amdgcn_mfma_f32_16x16x32_f16(vf, pb[0], O[0][u], 0, 0, 0);
      O[1][u] = __builtin_amdgcn_mfma_f32_16x16x32_f16(vf, pb[1], O[1][u], 0, 0, 0);
    }
    Lacc[0] = __builtin_amdgcn_mfma_f32_16x16x32_f16(ones, pb[0], Lacc[0], 0, 0, 0);
    Lacc[1] = __builtin_amdgcn_mfma_f32_16x16x32_f16(ones, pb[1], Lacc[1], 0, 0, 0);
  }

  // ---- epilogue: L row-sum lives at D[0][r]: lanes 0..15, reg 0.
  // O^T layout -> 4 consecutive douts per lane: contiguous dwordx4 stores.
#pragma unroll
  for (int rt = 0; rt < 2; ++rt) {
    float lv = __shfl(Lacc[rt][0], lm);
    float inv = 1.0f / fmaxf(lv, 1e-30f);
    float* po = out + (size_t)(rowbase + rt * 16 + lm) * DOUT + l4 * 4;
#pragma unroll
    for (int u = 0; u < 16; ++u) {
      f32x4 ov = O[rt][u] * inv;
      *(f32x4*)(po + u * 16) = ov;
    }
  }
}

extern "C" void kernel_launch(void* const* d_in, const int* in_sizes, int n_in,
                              void* d_out, int out_size, void* d_ws, size_t ws_size,
                              hipStream_t stream) {
  const float* x = (const float*)d_in[0];
  const float* ctrs = (const float*)d_in[1];
  const float* values = (const float*)d_in[2];
  const float* s = (const float*)d_in[3];
  float* out = (float*)d_out;
  char* ws = (char*)d_ws;

  hipLaunchKernelGGL(precompute_kernel, dim3(32), dim3(256), 0, stream,
                     ctrs, values, s, ws);
  hipLaunchKernelGGL(attn_kernel, dim3(512), dim3(256), 0, stream,
                     x, s, ws, out);
}